// Round 2
// baseline (32.324 us; speedup 1.0000x reference)
//
#include <hip/hip_runtime.h>

// YOLOv2 loss, fused single kernel + last-block reduction.
// B=1024, S=13, A=5, C5=25. preds [B,S,S,A,25] f32, labels [B,S,S,25] f32.
constexpr int kB     = 1024;
constexpr int kS     = 13;
constexpr int kA     = 5;
constexpr int kC5    = 25;
constexpr int kCells = kB * kS * kS;      // 173056
constexpr int kBlock = 256;
constexpr int kCPB   = 256;               // cells per block
constexpr int kNBlk  = kCells / kCPB;     // 676 (exact)
static_assert(kCells % kCPB == 0, "grid must tile exactly");

__global__ __launch_bounds__(kBlock)
void yolo_fused(const float* __restrict__ preds,
                const float* __restrict__ labels,
                float* __restrict__ out,
                float* __restrict__ partial,
                unsigned* __restrict__ counter)
{
    __shared__ float lab[kCPB * kC5];          // 25.6 KB, stride 25 (odd -> <=2-way)
    __shared__ float pbox[kCPB * 27];          // 27.6 KB, box+conf of obj cells, stride 27
    __shared__ unsigned short objIdx[kCPB];    // local cell ids of object cells
    __shared__ int   waveCnt[kBlock / 64];
    __shared__ int   amLast;
    __shared__ float sred[kBlock / 64];

    const int tid  = threadIdx.x;
    const int lane = tid & 63;
    const int wid  = tid >> 6;
    const size_t cellBase = (size_t)blockIdx.x * kCPB;

    // ---- 1) stage labels, fully coalesced float4 (block chunk is 16B aligned) ----
    {
        const float4* __restrict__ src = (const float4*)(labels + cellBase * kC5);
        float4* dst = (float4*)lab;
        #pragma unroll
        for (int i = 0; i < 6; ++i) dst[tid + i * kBlock] = src[tid + i * kBlock];
        if (tid < (kCPB * kC5 / 4) - 6 * kBlock)          // 1600 - 1536 = 64
            dst[tid + 6 * kBlock] = src[tid + 6 * kBlock];
    }
    __syncthreads();

    // ---- 2) compact object cells (ballot + prefix) ----
    const bool isObj = (lab[tid * kC5 + 4] == 1.0f);
    const unsigned long long mask = __ballot(isObj);
    if (lane == 0) waveCnt[wid] = __popcll(mask);
    __syncthreads();
    int nObj = 0, base = 0;
    #pragma unroll
    for (int w = 0; w < kBlock / 64; ++w) {
        int c = waveCnt[w];
        if (w < wid) base += c;
        nObj += c;
    }
    if (isObj) {
        int pre = __popcll(mask & ((1ull << lane) - 1ull));
        objIdx[base + pre] = (unsigned short)tid;
    }
    __syncthreads();

    // ---- 3) cooperative gather of box+conf (25 floats/anchor-set) for object cells ----
    {
        const float* __restrict__ pb = preds + cellBase * (kA * kC5);
        for (int idx = tid; idx < nObj * 25; idx += kBlock) {
            int k = idx / 25;              // object slot
            int f = idx - k * 25;          // 0..24  -> anchor a=f/5, field j=f%5
            int a = f / 5;
            int j = f - a * 5;
            int lc = objIdx[k];
            pbox[k * 27 + f] = pb[lc * (kA * kC5) + a * kC5 + j];
        }
    }
    __syncthreads();

    // ---- 4) per-object-cell loss ----
    float loss = 0.0f;
    if (tid < nObj) {
        const int lc = objIdx[tid];
        const float* __restrict__ L = lab + lc * kC5;
        const float  lx = L[0], ly = L[1], lw = L[2], lh = L[3];
        const float  lx1 = lx - lw * 0.5f, lx2 = lx + lw * 0.5f;
        const float  ly1 = ly - lh * 0.5f, ly2 = ly + lh * 0.5f;
        const float  larea = lw * lh;

        const float* __restrict__ P = pbox + tid * 27;   // [a*5 + j]
        float iou[kA], conf[kA];
        int best = 0;
        float bestIou = -1.0f;
        #pragma unroll
        for (int a = 0; a < kA; ++a) {
            float px = P[a * 5 + 0], py = P[a * 5 + 1];
            float pw = P[a * 5 + 2], ph = P[a * 5 + 3];
            conf[a] = P[a * 5 + 4];
            float px1 = px - pw * 0.5f, px2 = px + pw * 0.5f;
            float py1 = py - ph * 0.5f, py2 = py + ph * 0.5f;
            float iw = fmaxf(fminf(px2, lx2) - fmaxf(px1, lx1), 0.0f);
            float ih = fmaxf(fminf(py2, ly2) - fmaxf(py1, ly1), 0.0f);
            float inter = iw * ih;
            float uni = pw * ph + larea - inter;
            float v = inter / (uni + 1e-12f);
            iou[a] = v;
            if (v > bestIou) { bestIou = v; best = a; }  // strict > == jnp.argmax first-max
        }

        // xy
        float dx = lx - P[best * 5 + 0], dy = ly - P[best * 5 + 1];
        loss += 5.0f * (dx * dx + dy * dy);
        // wh
        float sw = sqrtf(lw) - sqrtf(P[best * 5 + 2]);
        float sh = sqrtf(lh) - sqrtf(P[best * 5 + 3]);
        loss += sw * sw + sh * sh;
        // obj
        float dob = bestIou - conf[best];
        loss += dob * dob;
        // cls: gather best anchor's 20 classes directly from global
        {
            const float* __restrict__ gp =
                preds + (cellBase + lc) * (kA * kC5) + best * kC5;
            float cls = 0.0f;
            #pragma unroll
            for (int c = 5; c < kC5; ++c) {
                float d = L[c] - gp[c];
                cls += d * d;
            }
            loss += cls;
        }
        // noobj
        #pragma unroll
        for (int a = 0; a < kA; ++a) {
            if (a != best && iou[a] < 0.6f) {
                float d = iou[a] - conf[a];
                loss += d * d;
            }
        }
    }

    // ---- 5) block reduction ----
    #pragma unroll
    for (int off = 32; off > 0; off >>= 1)
        loss += __shfl_down(loss, off, 64);
    if (lane == 0) sred[wid] = loss;
    __syncthreads();
    if (tid == 0) {
        float s = sred[0] + sred[1] + sred[2] + sred[3];
        __hip_atomic_store(&partial[blockIdx.x], s, __ATOMIC_RELAXED,
                           __HIP_MEMORY_SCOPE_AGENT);
        unsigned old = __hip_atomic_fetch_add(counter, 1u, __ATOMIC_ACQ_REL,
                                              __HIP_MEMORY_SCOPE_AGENT);
        amLast = (old == kNBlk - 1) ? 1 : 0;
    }
    __syncthreads();

    // ---- 6) last block: final reduce over partials ----
    if (amLast) {
        float s = 0.0f;
        for (int i = tid; i < kNBlk; i += kBlock)
            s += __hip_atomic_load(&partial[i], __ATOMIC_RELAXED,
                                   __HIP_MEMORY_SCOPE_AGENT);
        #pragma unroll
        for (int off = 32; off > 0; off >>= 1)
            s += __shfl_down(s, off, 64);
        if (lane == 0) sred[wid] = s;
        __syncthreads();
        if (tid == 0)
            out[0] = (sred[0] + sred[1] + sred[2] + sred[3]) * (1.0f / (float)kB);
    }
}

extern "C" void kernel_launch(void* const* d_in, const int* in_sizes, int n_in,
                              void* d_out, int out_size, void* d_ws, size_t ws_size,
                              hipStream_t stream) {
    const float* preds  = (const float*)d_in[0];
    const float* labels = (const float*)d_in[1];
    float* out = (float*)d_out;

    unsigned* counter = (unsigned*)d_ws;                    // 4 B
    float* partial    = (float*)((char*)d_ws + 256);        // 676 floats

    // d_ws is poisoned 0xAA and NOT re-poisoned between replays: zero the
    // counter every call (hipMemsetAsync is graph-capture safe).
    hipMemsetAsync(counter, 0, sizeof(unsigned), stream);
    yolo_fused<<<kNBlk, kBlock, 0, stream>>>(preds, labels, out, partial, counter);
}